// Round 3
// baseline (167.172 us; speedup 1.0000x reference)
//
#include <hip/hip_runtime.h>
#include <hip/hip_bf16.h>

// FactorizedTrilinear: out[b,z,x,c,dv] = sum_e p1[b,z,dv,e] p2[b,x,dv,e] p3[b,c,dv,e]
// B=4, Z=128, DV=4, IN=512, R=256. Output 4*128^3*4 fp32 = 134 MB (write-bound).
// Stage 1: p_k = x_k@W_k + b_k via bf16 MFMA (p1 stored bf16, p2/p3 f32).
// Stage 2: zero-LDS, zero-barrier MFMA stream; B-operand built in-register.
// NOTE: all f32->bf16 conversions via f2bf (R1-verified). v_cvt_pk_bf16_f32
// was the R2 failure suspect (pack order mismatch vs linear memory order).

typedef __attribute__((ext_vector_type(8))) short short8;
typedef __attribute__((ext_vector_type(4))) float f32x4;

__device__ __forceinline__ short f2bf(float f) {
    union { float f; unsigned u; } v; v.f = f;
    unsigned r = v.u + 0x7FFFu + ((v.u >> 16) & 1u);   // RNE to bf16
    return (short)(r >> 16);
}

// ---------------- Stage 1: projections via MFMA ----------------
// GEMM per matrix: M=2048 (rows m = b*512 + z*4 + dv), N=256 (r), K=512.
// Wave tile 16m x 32n; block = 4 waves (2m x 2n) = 32m x 64n.
// Grid (64 m-tiles, 4 n-tiles, 3 matrices). All fragment loads per-lane direct
// from global (no LDS, no barriers).
__global__ __launch_bounds__(256) void proj_kernel(
    const float* __restrict__ x1, const float* __restrict__ x2, const float* __restrict__ x3,
    const float* __restrict__ W1, const float* __restrict__ b1,
    const float* __restrict__ W2, const float* __restrict__ b2,
    const float* __restrict__ W3, const float* __restrict__ b3,
    short* __restrict__ p1, float* __restrict__ p2, float* __restrict__ p3) {
    const int mat = blockIdx.z;
    const float* __restrict__ x    = (mat == 0) ? x1 : (mat == 1) ? x2 : x3;
    const float* __restrict__ W    = (mat == 0) ? W1 : (mat == 1) ? W2 : W3;
    const float* __restrict__ bias = (mat == 0) ? b1 : (mat == 1) ? b2 : b3;

    const int tid  = threadIdx.x;
    const int lane = tid & 63;
    const int w    = tid >> 6;
    const int kq   = lane >> 4, ln = lane & 15;
    const int m_base = blockIdx.x * 32 + (w >> 1) * 16;
    const int n_base = blockIdx.y * 64 + (w & 1) * 32;

    f32x4 acc[2];
    acc[0] = (f32x4){0.f, 0.f, 0.f, 0.f};
    acc[1] = (f32x4){0.f, 0.f, 0.f, 0.f};

#pragma unroll 1
    for (int ks = 0; ks < 16; ++ks) {
        const int k0 = ks * 32 + kq * 8;
        // A fragment: x[m_base+ln][k0..k0+8) -> bf16 (linear j -> k order)
        const float* X = x + (size_t)(m_base + ln) * 512 + k0;
        f32x4 a0 = *(const f32x4*)X;
        f32x4 a1 = *(const f32x4*)(X + 4);
        short8 av;
        av[0] = f2bf(a0[0]); av[1] = f2bf(a0[1]);
        av[2] = f2bf(a0[2]); av[3] = f2bf(a0[3]);
        av[4] = f2bf(a1[0]); av[5] = f2bf(a1[1]);
        av[6] = f2bf(a1[2]); av[7] = f2bf(a1[3]);
#pragma unroll
        for (int nt = 0; nt < 2; ++nt) {
            const int n = n_base + nt * 16 + ln;
            short8 bv;
#pragma unroll
            for (int j = 0; j < 8; ++j) bv[j] = f2bf(W[(k0 + j) * 256 + n]);
            acc[nt] = __builtin_amdgcn_mfma_f32_16x16x32_bf16(av, bv, acc[nt], 0, 0, 0);
        }
    }

    // Epilogue: C[m][n], row m = (lane>>4)*4 + reg, col n = lane&15 (verified map).
#pragma unroll
    for (int nt = 0; nt < 2; ++nt) {
        const int n = n_base + nt * 16 + ln;
        const float bn = bias[n];
#pragma unroll
        for (int r = 0; r < 4; ++r) {
            const int m  = m_base + kq * 4 + r;
            const int bb = m >> 9, z = (m >> 2) & 127, dv = m & 3;
            const int off = ((bb * 4 + dv) * 128 + z) * 256 + n;
            const float val = acc[nt][r] + bn;
            if (mat == 0)      p1[off] = f2bf(val);
            else if (mat == 1) p2[off] = val;
            else               p3[off] = val;
        }
    }
}

// ---------------- Stage 2: trilinear, zero-LDS zero-barrier ----------------
// Block = (b, x, zh): 4 waves, wave w owns c-quarter [w*32, w*32+32), z-half
// [zh*64, zh*64+64). acc[4 zt][2 c2][4 dv] = 128 VGPR. All fragments loaded
// per-lane from L2-resident p1/p2/p3; B = bf16(p3 * p2_broadcast) in-register.
__global__ __launch_bounds__(256, 2) void tri_kernel(
    const short* __restrict__ p1, const float* __restrict__ p2,
    const float* __restrict__ p3, float* __restrict__ out) {
    const int bi = blockIdx.x;
    const int zh = bi & 1;
    const int x  = (bi >> 1) & 127;
    const int b  = bi >> 8;

    const int tid  = threadIdx.x;
    const int lane = tid & 63;
    const int w    = tid >> 6;
    const int kq   = lane >> 4, ln = lane & 15;
    const int z0   = zh * 64;
    const int c0   = w * 32;

    f32x4 acc[4][2][4];
    const f32x4 zero = {0.f, 0.f, 0.f, 0.f};
#pragma unroll
    for (int zt = 0; zt < 4; ++zt)
#pragma unroll
        for (int c2 = 0; c2 < 2; ++c2)
#pragma unroll
            for (int dv = 0; dv < 4; ++dv) acc[zt][c2][dv] = zero;

#pragma unroll 1
    for (int chunk = 0; chunk < 8; ++chunk) {
        const int e0 = chunk * 32 + kq * 8;   // this lane's k-slice
#pragma unroll
        for (int dv = 0; dv < 4; ++dv) {
            const int sl = b * 4 + dv;
            // p2 scale row (wave-broadcast within kq group)
            const float* P2 = p2 + ((sl * 128 + x) << 8) + e0;
            f32x4 s0 = *(const f32x4*)P2;
            f32x4 s1 = *(const f32x4*)(P2 + 4);
            // A fragments: p1 rows z0+zt*16+ln (linear j -> e order)
            short8 af[4];
#pragma unroll
            for (int zt = 0; zt < 4; ++zt)
                af[zt] = *(const short8*)(p1 + ((sl * 128 + z0 + zt * 16 + ln) << 8) + e0);
#pragma unroll
            for (int c2 = 0; c2 < 2; ++c2) {
                const float* P3 = p3 + ((sl * 128 + c0 + c2 * 16 + ln) << 8) + e0;
                f32x4 q0 = *(const f32x4*)P3;
                f32x4 q1 = *(const f32x4*)(P3 + 4);
                short8 bv;
                bv[0] = f2bf(s0[0] * q0[0]); bv[1] = f2bf(s0[1] * q0[1]);
                bv[2] = f2bf(s0[2] * q0[2]); bv[3] = f2bf(s0[3] * q0[3]);
                bv[4] = f2bf(s1[0] * q1[0]); bv[5] = f2bf(s1[1] * q1[1]);
                bv[6] = f2bf(s1[2] * q1[2]); bv[7] = f2bf(s1[3] * q1[3]);
#pragma unroll
                for (int zt = 0; zt < 4; ++zt)
                    acc[zt][c2][dv] = __builtin_amdgcn_mfma_f32_16x16x32_bf16(
                        af[zt], bv, acc[zt][c2][dv], 0, 0, 0);
            }
        }
    }

    // Epilogue: float4 over dv (innermost out dims) -> 16B coalesced stores.
#pragma unroll
    for (int zt = 0; zt < 4; ++zt)
#pragma unroll
        for (int c2 = 0; c2 < 2; ++c2)
#pragma unroll
            for (int r = 0; r < 4; ++r) {
                const int z = z0 + zt * 16 + kq * 4 + r;
                const int c = c0 + c2 * 16 + ln;
                const size_t idx = (size_t)((b * 128 + z) * 128 + x) * 128 + c;
                f32x4 v;
                v[0] = acc[zt][c2][0][r];
                v[1] = acc[zt][c2][1][r];
                v[2] = acc[zt][c2][2][r];
                v[3] = acc[zt][c2][3][r];
                *(f32x4*)(out + idx * 4) = v;
            }
}

extern "C" void kernel_launch(void* const* d_in, const int* in_sizes, int n_in,
                              void* d_out, int out_size, void* d_ws, size_t ws_size,
                              hipStream_t stream) {
    const float* x1 = (const float*)d_in[0];
    const float* x2 = (const float*)d_in[1];
    const float* x3 = (const float*)d_in[2];
    const float* W1 = (const float*)d_in[3];
    const float* b1 = (const float*)d_in[4];
    const float* W2 = (const float*)d_in[5];
    const float* b2 = (const float*)d_in[6];
    const float* W3 = (const float*)d_in[7];
    const float* b3 = (const float*)d_in[8];

    char* ws = (char*)d_ws;
    short* p1 = (short*)ws;                       // bf16 [16][128][256] = 1 MB
    float* p2 = (float*)(ws + (1u << 20));        // f32  [16][128][256] = 2 MB
    float* p3 = (float*)(ws + 3u * (1u << 20));   // f32  [16][128][256] = 2 MB

    proj_kernel<<<dim3(64, 4, 3), 256, 0, stream>>>(x1, x2, x3, W1, b1, W2, b2, W3, b3,
                                                    p1, p2, p3);
    tri_kernel<<<dim3(1024), 256, 0, stream>>>(p1, p2, p3, (float*)d_out);
}

// Round 4
// 122.922 us; speedup vs baseline: 1.3600x; 1.3600x over previous
//
#include <hip/hip_runtime.h>
#include <hip/hip_bf16.h>

// FactorizedTrilinear: out[b,z,x,c,dv] = sum_e p1[b,z,dv,e] p2[b,x,dv,e] p3[b,c,dv,e]
// B=4, Z=128, DV=4, IN=512, R=256. Output 4*128^3*4 fp32 = 134 MB (write-bound).
// R4: all-f16 pipeline. wt_kernel transposes W -> Wt[r][k] f16; proj_kernel does
// p_k = x_k@W_k + b_k via f16 MFMA (contiguous Wt B-frags); tri_kernel is an
// LDS-staged double-buffered MFMA kernel, B-operand = pk_mul_f16(p2,p3).

typedef _Float16 f16;
typedef __attribute__((ext_vector_type(8))) _Float16 f16x8;
typedef __attribute__((ext_vector_type(4))) float f32x4;

// ---------------- Stage 0: W transpose + f16 convert ----------------
// Wt[mat][n][k] = (f16) W[mat][k][n];  W: [512][256] f32, Wt: [256][512] f16.
__global__ __launch_bounds__(256) void wt_kernel(
    const float* __restrict__ W1, const float* __restrict__ W2, const float* __restrict__ W3,
    f16* __restrict__ Wt) {
    const int mat = blockIdx.z;
    const float* __restrict__ W = (mat == 0) ? W1 : (mat == 1) ? W2 : W3;
    f16* __restrict__ T = Wt + (size_t)mat * 256 * 512;
    const int k0 = blockIdx.x * 64, n0 = blockIdx.y * 64;
    __shared__ float tile[64][65];
    const int t = threadIdx.x;
    const int c = t & 63, r4 = t >> 6;
#pragma unroll
    for (int i = 0; i < 16; ++i) {
        const int k = r4 * 16 + i;
        tile[k][c] = W[(size_t)(k0 + k) * 256 + n0 + c];
    }
    __syncthreads();
#pragma unroll
    for (int i = 0; i < 16; ++i) {
        const int n = r4 * 16 + i;
        T[(size_t)(n0 + n) * 512 + k0 + c] = (f16)tile[c][n];
    }
}

// ---------------- Stage 1: projections via f16 MFMA ----------------
// GEMM per matrix: M=2048 (rows m = b*512 + z*4 + dv), N=256, K=512.
// Wave tile 16m x 32n; block 4 waves = 32m x 64n; grid (64,4,3). No LDS/barriers.
__global__ __launch_bounds__(256) void proj_kernel(
    const float* __restrict__ x1, const float* __restrict__ x2, const float* __restrict__ x3,
    const f16* __restrict__ Wt,
    const float* __restrict__ b1, const float* __restrict__ b2, const float* __restrict__ b3,
    f16* __restrict__ p1, f16* __restrict__ p2, f16* __restrict__ p3) {
    const int mat = blockIdx.z;
    const float* __restrict__ x    = (mat == 0) ? x1 : (mat == 1) ? x2 : x3;
    const f16*   __restrict__ T    = Wt + (size_t)mat * 131072;
    const float* __restrict__ bias = (mat == 0) ? b1 : (mat == 1) ? b2 : b3;
    f16* __restrict__ p = (mat == 0) ? p1 : (mat == 1) ? p2 : p3;

    const int tid  = threadIdx.x;
    const int lane = tid & 63;
    const int w    = tid >> 6;
    const int kq   = lane >> 4, ln = lane & 15;
    const int m_base = blockIdx.x * 32 + (w >> 1) * 16;
    const int n_base = blockIdx.y * 64 + (w & 1) * 32;

    f32x4 acc[2];
    acc[0] = (f32x4){0.f, 0.f, 0.f, 0.f};
    acc[1] = (f32x4){0.f, 0.f, 0.f, 0.f};

#pragma unroll 1
    for (int ks = 0; ks < 16; ++ks) {
        const int k0 = ks * 32 + kq * 8;
        const float* X = x + (size_t)(m_base + ln) * 512 + k0;
        f32x4 a0 = *(const f32x4*)X;
        f32x4 a1 = *(const f32x4*)(X + 4);
        f16x8 av;
        av[0] = (f16)a0[0]; av[1] = (f16)a0[1]; av[2] = (f16)a0[2]; av[3] = (f16)a0[3];
        av[4] = (f16)a1[0]; av[5] = (f16)a1[1]; av[6] = (f16)a1[2]; av[7] = (f16)a1[3];
#pragma unroll
        for (int nt = 0; nt < 2; ++nt) {
            const int n = n_base + nt * 16 + ln;
            f16x8 bv = *(const f16x8*)(T + (size_t)n * 512 + k0);
            acc[nt] = __builtin_amdgcn_mfma_f32_16x16x32_f16(av, bv, acc[nt], 0, 0, 0);
        }
    }

    // C map (verified): row m = (lane>>4)*4 + reg, col n = lane&15.
#pragma unroll
    for (int nt = 0; nt < 2; ++nt) {
        const int n = n_base + nt * 16 + ln;
        const float bn = bias[n];
#pragma unroll
        for (int r = 0; r < 4; ++r) {
            const int m  = m_base + kq * 4 + r;
            const int bb = m >> 9, z = (m >> 2) & 127, dv = m & 3;
            p[((bb * 4 + dv) * 128 + z) * 256 + n] = (f16)(acc[nt][r] + bn);
        }
    }
}

// ---------------- Stage 2: trilinear, LDS-staged double-buffered ----------------
// Block = (b, x, zh): tile 64z x 128c x 4dv. 8 waves = (zq in 2) x (cq in 4),
// wave tile 32z x 32c x 4dv -> acc 16 frags = 64 AGPR.
// Per 32-e chunk: sA granules (dv*4+kg)*64+z' (16KB), sQ (dv*4+kg)*128+c (32KB),
// double-buffered = 96 KB LDS. Q granule = pk_mul_f16(p2 slice, p3 slice).
__global__ __launch_bounds__(512) void tri_kernel(
    const f16* __restrict__ p1, const f16* __restrict__ p2,
    const f16* __restrict__ p3, float* __restrict__ out) {
    const int bi = blockIdx.x;
    const int zh = bi & 1;
    const int x  = (bi >> 1) & 127;
    const int b  = bi >> 8;

    const int tid  = threadIdx.x;
    const int lane = tid & 63;
    const int w    = tid >> 6;
    const int zq   = w >> 2, cq = w & 3;
    const int kq   = lane >> 4, ln = lane & 15;

    __shared__ __align__(16) f16 sA[2][1024 * 8];   // 2 x 16 KB
    __shared__ __align__(16) f16 sQ[2][2048 * 8];   // 2 x 32 KB

    f32x4 acc[2][2][4];
    const f32x4 zero = {0.f, 0.f, 0.f, 0.f};
#pragma unroll
    for (int zt = 0; zt < 2; ++zt)
#pragma unroll
        for (int c2 = 0; c2 < 2; ++c2)
#pragma unroll
            for (int dv = 0; dv < 4; ++dv) acc[zt][c2][dv] = zero;

    // ---- prologue: stage chunk 0 into buf 0 ----
    {
#pragma unroll
        for (int it = 0; it < 2; ++it) {
            const int g = it * 512 + tid;
            const int dv = g >> 8, kg = (g >> 6) & 3, z2 = g & 63;
            f16x8 v = *(const f16x8*)(p1 + (((b * 4 + dv) * 128 + zh * 64 + z2) << 8) + kg * 8);
            *(f16x8*)&sA[0][g * 8] = v;
        }
#pragma unroll
        for (int it = 0; it < 4; ++it) {
            const int g = it * 512 + tid;
            const int dv = g >> 9, kg = (g >> 7) & 3, cc = g & 127;
            f16x8 s2 = *(const f16x8*)(p2 + (((b * 4 + dv) * 128 + x) << 8) + kg * 8);
            f16x8 s3 = *(const f16x8*)(p3 + (((b * 4 + dv) * 128 + cc) << 8) + kg * 8);
            f16x8 q = s2 * s3;   // v_pk_mul_f16 x4
            *(f16x8*)&sQ[0][g * 8] = q;
        }
    }
    __syncthreads();

    int buf = 0;
#pragma unroll 1
    for (int ch = 0; ch < 8; ++ch) {
        const int nb = buf ^ 1;
        f16x8 a_st[2], s2v[4], s3v[4];
        const bool pf = (ch < 7);
        if (pf) {
            const int e1 = (ch + 1) * 32;
#pragma unroll
            for (int it = 0; it < 2; ++it) {
                const int g = it * 512 + tid;
                const int dv = g >> 8, kg = (g >> 6) & 3, z2 = g & 63;
                a_st[it] = *(const f16x8*)(p1 + (((b * 4 + dv) * 128 + zh * 64 + z2) << 8) + e1 + kg * 8);
            }
#pragma unroll
            for (int it = 0; it < 4; ++it) {
                const int g = it * 512 + tid;
                const int dv = g >> 9, kg = (g >> 7) & 3, cc = g & 127;
                s2v[it] = *(const f16x8*)(p2 + (((b * 4 + dv) * 128 + x) << 8) + e1 + kg * 8);
                s3v[it] = *(const f16x8*)(p3 + (((b * 4 + dv) * 128 + cc) << 8) + e1 + kg * 8);
            }
        }

        // ---- compute current buffer: 16 ds_read_b128 + 16 MFMA ----
#pragma unroll
        for (int dv = 0; dv < 4; ++dv) {
            f16x8 af[2], bf[2];
#pragma unroll
            for (int zt = 0; zt < 2; ++zt)
                af[zt] = *(const f16x8*)&sA[buf][((dv * 4 + kq) * 64 + zq * 32 + zt * 16 + ln) * 8];
#pragma unroll
            for (int c2 = 0; c2 < 2; ++c2)
                bf[c2] = *(const f16x8*)&sQ[buf][((dv * 4 + kq) * 128 + cq * 32 + c2 * 16 + ln) * 8];
#pragma unroll
            for (int zt = 0; zt < 2; ++zt)
#pragma unroll
                for (int c2 = 0; c2 < 2; ++c2)
                    acc[zt][c2][dv] = __builtin_amdgcn_mfma_f32_16x16x32_f16(
                        af[zt], bf[c2], acc[zt][c2][dv], 0, 0, 0);
        }

        if (pf) {
#pragma unroll
            for (int it = 0; it < 2; ++it) {
                const int g = it * 512 + tid;
                *(f16x8*)&sA[nb][g * 8] = a_st[it];
            }
#pragma unroll
            for (int it = 0; it < 4; ++it) {
                const int g = it * 512 + tid;
                f16x8 q = s2v[it] * s3v[it];
                *(f16x8*)&sQ[nb][g * 8] = q;
            }
        }
        __syncthreads();
        buf = nb;
    }

    // ---- epilogue: float4 over dv (innermost out dims), coalesced ----
#pragma unroll
    for (int zt = 0; zt < 2; ++zt)
#pragma unroll
        for (int c2 = 0; c2 < 2; ++c2)
#pragma unroll
            for (int r = 0; r < 4; ++r) {
                const int z = zh * 64 + zq * 32 + zt * 16 + kq * 4 + r;
                const int c = cq * 32 + c2 * 16 + ln;
                const size_t idx = (size_t)((b * 128 + z) * 128 + x) * 128 + c;
                f32x4 v;
                v[0] = acc[zt][c2][0][r];
                v[1] = acc[zt][c2][1][r];
                v[2] = acc[zt][c2][2][r];
                v[3] = acc[zt][c2][3][r];
                *(f32x4*)(out + idx * 4) = v;
            }
}

extern "C" void kernel_launch(void* const* d_in, const int* in_sizes, int n_in,
                              void* d_out, int out_size, void* d_ws, size_t ws_size,
                              hipStream_t stream) {
    const float* x1 = (const float*)d_in[0];
    const float* x2 = (const float*)d_in[1];
    const float* x3 = (const float*)d_in[2];
    const float* W1 = (const float*)d_in[3];
    const float* b1 = (const float*)d_in[4];
    const float* W2 = (const float*)d_in[5];
    const float* b2 = (const float*)d_in[6];
    const float* W3 = (const float*)d_in[7];
    const float* b3 = (const float*)d_in[8];

    char* ws = (char*)d_ws;
    f16* p1 = (f16*)ws;                            // [16][128][256] f16 = 1 MB
    f16* p2 = (f16*)(ws + (1u << 20));             // 1 MB
    f16* p3 = (f16*)(ws + 2u * (1u << 20));        // 1 MB
    f16* Wt = (f16*)(ws + 3u * (1u << 20));        // 3 x 256 KB

    wt_kernel<<<dim3(8, 4, 3), 256, 0, stream>>>(W1, W2, W3, Wt);
    proj_kernel<<<dim3(64, 4, 3), 256, 0, stream>>>(x1, x2, x3, Wt, b1, b2, b3,
                                                    p1, p2, p3);
    tri_kernel<<<dim3(1024), 512, 0, stream>>>(p1, p2, p3, (float*)d_out);
}